// Round 1
// baseline (380.413 us; speedup 1.0000x reference)
//
#include <hip/hip_runtime.h>
#include <hip/hip_bf16.h>
#include <stdint.h>

// Problem constants: B=8, N=2048, E=1024, H=16, D=64 -> M = B*N = 16384.
// qkv row layout per token: [3][H=16][D=64] = 3072 elems (q: 0..1023, k: 1024..2047, v: 2048..3071)

typedef __attribute__((ext_vector_type(8))) short short8;
typedef __attribute__((ext_vector_type(8))) unsigned short ushort8;
typedef __attribute__((ext_vector_type(4))) float floatx4;

__device__ __forceinline__ unsigned short f2bf(float f) {
  union { float f; uint32_t u; } x; x.f = f;
  uint32_t u = x.u;
  return (unsigned short)((u + 0x7fffu + ((u >> 16) & 1u)) >> 16);  // RNE
}
__device__ __forceinline__ float bf2f(unsigned short s) {
  union { uint32_t u; float f; } x; x.u = ((uint32_t)s) << 16; return x.f;
}

// ---------------- fp32 -> bf16 cast, 8 elems/thread ----------------
__global__ __launch_bounds__(256) void cvt_kernel(const float* __restrict__ in,
                                                  unsigned short* __restrict__ out, int n8) {
  int i = blockIdx.x * 256 + threadIdx.x;
  if (i >= n8) return;
  long base = (long)i * 8;
  const float4* p = (const float4*)(in + base);
  float4 a = p[0], b = p[1];
  ushort8 r;
  r[0] = f2bf(a.x); r[1] = f2bf(a.y); r[2] = f2bf(a.z); r[3] = f2bf(a.w);
  r[4] = f2bf(b.x); r[5] = f2bf(b.y); r[6] = f2bf(b.z); r[7] = f2bf(b.w);
  *(ushort8*)(out + base) = r;
}

// ---------------- async global->LDS, 16B per lane ----------------
__device__ __forceinline__ void gl2lds16(const void* g, void* l) {
  __builtin_amdgcn_global_load_lds(
      (const uint32_t __attribute__((address_space(1)))*)g,
      (uint32_t __attribute__((address_space(3)))*)(uint32_t)(uintptr_t)l,
      16, 0, 0);
}

// ---------------- bf16 GEMM: C[M,N] = A[M,K] * B[N,K]^T + bias[N] ----------------
// m97 structure: 128x128 block tile, BK=32, 4 waves each 64x64 (4x4 of 16x16x32 MFMA).
template <bool OUT_BF16>
__global__ __launch_bounds__(256) void gemm_bt(const unsigned short* __restrict__ A,
                                               const unsigned short* __restrict__ Bm,
                                               const float* __restrict__ bias,
                                               void* __restrict__ Cout,
                                               int M, int N, int K) {
  __shared__ __align__(16) unsigned short lA[128 * 32];
  __shared__ __align__(16) unsigned short lB[128 * 32];
  const int tid = threadIdx.x;
  const long row0 = (long)blockIdx.y * 128;
  const long col0 = (long)blockIdx.x * 128;
  const int lane = tid & 63;
  const int wave = tid >> 6;
  const int wr = (wave & 1) * 64;   // wave row offset in tile
  const int wc = (wave >> 1) * 64;  // wave col offset in tile
  const int q4 = lane >> 4;         // quad 0..3
  const int l16 = lane & 15;

  floatx4 acc[4][4] = {};

  // staging: thread t covers row t/4, cols (t%4)*8 .. +8 (16B); two insts cover 128 rows
  const unsigned short* gA0 = A + (row0 + (tid >> 2)) * (long)K + (tid & 3) * 8;
  const unsigned short* gB0 = Bm + (col0 + (tid >> 2)) * (long)K + (tid & 3) * 8;
  char* lA_dst = (char*)lA + tid * 16;  // == wave_base + lane*16 (required layout)
  char* lB_dst = (char*)lB + tid * 16;
  const long stride64 = (long)64 * K;

  for (int k0 = 0; k0 < K; k0 += 32) {
    __syncthreads();
    gl2lds16(gA0 + k0, lA_dst);
    gl2lds16(gA0 + stride64 + k0, lA_dst + 4096);
    gl2lds16(gB0 + k0, lB_dst);
    gl2lds16(gB0 + stride64 + k0, lB_dst + 4096);
    __syncthreads();

    short8 af[4], bfr[4];
#pragma unroll
    for (int i = 0; i < 4; i++)
      af[i] = *(const short8*)&lA[(wr + i * 16 + l16) * 32 + q4 * 8];
#pragma unroll
    for (int j = 0; j < 4; j++)
      bfr[j] = *(const short8*)&lB[(wc + j * 16 + l16) * 32 + q4 * 8];
#pragma unroll
    for (int i = 0; i < 4; i++)
#pragma unroll
      for (int j = 0; j < 4; j++)
        acc[i][j] = __builtin_amdgcn_mfma_f32_16x16x32_bf16(af[i], bfr[j], acc[i][j], 0, 0, 0);
  }

  // epilogue: C/D layout col = lane&15, row = quad*4 + reg
  float bv[4];
#pragma unroll
  for (int j = 0; j < 4; j++) bv[j] = bias[col0 + wc + j * 16 + l16];

#pragma unroll
  for (int i = 0; i < 4; i++) {
#pragma unroll
    for (int j = 0; j < 4; j++) {
      const long col = col0 + wc + j * 16 + l16;
#pragma unroll
      for (int r = 0; r < 4; r++) {
        const long row = row0 + wr + i * 16 + q4 * 4 + r;
        float v = acc[i][j][r] + bv[j];
        if (OUT_BF16)
          ((unsigned short*)Cout)[row * N + col] = f2bf(v);
        else
          ((float*)Cout)[row * N + col] = v;
      }
    }
  }
}

// ---------------- per-token cross-head attention ----------------
// energy[b,s,i,j] = sum_d Q[b,s,i,d]*K[b,s,j,d] / 32; softmax over j (head axis);
// out[b,i,s,d] = sum_j A[i,j]*V[b,s,j,d]; written with the raw-reshape scramble:
// out2 row = b*2048 + i*128 + s/16, col = (s%16)*64 + d.
__global__ __launch_bounds__(256) void attn_kernel(const unsigned short* __restrict__ qkv,
                                                   unsigned short* __restrict__ out2) {
  const int t = blockIdx.x * 256 + threadIdx.x;  // (token, head)
  const int head = t & 15;
  const int token = t >> 4;
  const int b = token >> 11;
  const int s = token & 2047;
  const unsigned short* base = qkv + (long)token * 3072;

  // q row -> fp32
  float qf[64];
  {
    const uint4* qp = (const uint4*)(base + head * 64);
#pragma unroll
    for (int w = 0; w < 8; w++) {
      uint4 u = qp[w];
      uint32_t arr[4] = {u.x, u.y, u.z, u.w};
#pragma unroll
      for (int c = 0; c < 4; c++) {
        qf[w * 8 + c * 2 + 0] = bf2f((unsigned short)(arr[c] & 0xffffu));
        qf[w * 8 + c * 2 + 1] = bf2f((unsigned short)(arr[c] >> 16));
      }
    }
  }

  float e[16];
  const unsigned short* kbase = base + 1024;
  for (int j = 0; j < 16; j++) {
    const uint4* kp = (const uint4*)(kbase + j * 64);
    float acc = 0.f;
#pragma unroll
    for (int w = 0; w < 8; w++) {
      uint4 u = kp[w];
      uint32_t arr[4] = {u.x, u.y, u.z, u.w};
#pragma unroll
      for (int c = 0; c < 4; c++) {
        acc += qf[w * 8 + c * 2 + 0] * bf2f((unsigned short)(arr[c] & 0xffffu));
        acc += qf[w * 8 + c * 2 + 1] * bf2f((unsigned short)(arr[c] >> 16));
      }
    }
    e[j] = acc * 0.03125f;  // / sqrt(E=1024)
  }

  float mx = e[0];
#pragma unroll
  for (int j = 1; j < 16; j++) mx = fmaxf(mx, e[j]);
  float p[16];
  float sum = 0.f;
#pragma unroll
  for (int j = 0; j < 16; j++) { p[j] = __expf(e[j] - mx); sum += p[j]; }
  const float inv = 1.f / sum;

  float o[64];
#pragma unroll
  for (int d = 0; d < 64; d++) o[d] = 0.f;
  const unsigned short* vbase = base + 2048;
  for (int j = 0; j < 16; j++) {
    const float wgt = p[j] * inv;
    const uint4* vp = (const uint4*)(vbase + j * 64);
#pragma unroll
    for (int w = 0; w < 8; w++) {
      uint4 u = vp[w];
      uint32_t arr[4] = {u.x, u.y, u.z, u.w};
#pragma unroll
      for (int c = 0; c < 4; c++) {
        o[w * 8 + c * 2 + 0] += wgt * bf2f((unsigned short)(arr[c] & 0xffffu));
        o[w * 8 + c * 2 + 1] += wgt * bf2f((unsigned short)(arr[c] >> 16));
      }
    }
  }

  const long row = (long)b * 2048 + head * 128 + (s >> 4);
  unsigned short* op = out2 + row * 1024 + (long)(s & 15) * 64;
#pragma unroll
  for (int w = 0; w < 8; w++) {
    ushort8 r;
#pragma unroll
    for (int c = 0; c < 8; c++) r[c] = f2bf(o[w * 8 + c]);
    *(ushort8*)(op + w * 8) = r;
  }
}

extern "C" void kernel_launch(void* const* d_in, const int* in_sizes, int n_in,
                              void* d_out, int out_size, void* d_ws, size_t ws_size,
                              hipStream_t stream) {
  const float* x    = (const float*)d_in[0];  // [8,2048,1024]
  const float* Wqkv = (const float*)d_in[1];  // [3072,1024]
  const float* bqkv = (const float*)d_in[2];  // [3072]
  const float* Wo   = (const float*)d_in[3];  // [1024,1024]
  const float* bo   = (const float*)d_in[4];  // [1024]
  float* out = (float*)d_out;                 // [8,2048,1024] fp32

  char* ws = (char*)d_ws;
  unsigned short* x_bf    = (unsigned short*)(ws);                          // 32 MB
  unsigned short* wqkv_bf = (unsigned short*)(ws + 33554432);               // 6 MB
  unsigned short* wo_bf   = (unsigned short*)(ws + 39845888);               // 2 MB
  unsigned short* qkv_bf  = (unsigned short*)(ws + 41943040);               // 96 MB
  unsigned short* out2_bf = (unsigned short*)(ws + 142606336);              // 32 MB
  // total 176,160,768 B

  // casts
  cvt_kernel<<<8192, 256, 0, stream>>>(x, x_bf, 16777216 / 8);
  cvt_kernel<<<1536, 256, 0, stream>>>(Wqkv, wqkv_bf, 3145728 / 8);
  cvt_kernel<<<512, 256, 0, stream>>>(Wo, wo_bf, 1048576 / 8);

  // qkv = x @ Wqkv^T + bqkv   (M=16384, N=3072, K=1024), bf16 out
  dim3 g1(3072 / 128, 16384 / 128);
  gemm_bt<true><<<g1, 256, 0, stream>>>(x_bf, wqkv_bf, bqkv, qkv_bf, 16384, 3072, 1024);

  // per-token attention + scrambled reshape, bf16 out
  attn_kernel<<<1024, 256, 0, stream>>>(qkv_bf, out2_bf);

  // out = out2 @ Wo^T + bo    (M=16384, N=1024, K=1024), fp32 out
  dim3 g2(1024 / 128, 16384 / 128);
  gemm_bt<false><<<g2, 256, 0, stream>>>(out2_bf, wo_bf, bo, out, 16384, 1024, 1024);
}

// Round 2
// 357.819 us; speedup vs baseline: 1.0631x; 1.0631x over previous
//
#include <hip/hip_runtime.h>
#include <hip/hip_bf16.h>
#include <stdint.h>

// B=8, N=2048, E=1024, H=16, D=64 -> M = B*N = 16384.
// qkv row layout per token: [3][H=16][D=64] = 3072 elems

typedef __attribute__((ext_vector_type(8))) short short8;
typedef __attribute__((ext_vector_type(8))) unsigned short ushort8;
typedef __attribute__((ext_vector_type(16))) float floatx16;

__device__ __forceinline__ unsigned short f2bf(float f) {
  union { float f; uint32_t u; } x; x.f = f;
  uint32_t u = x.u;
  return (unsigned short)((u + 0x7fffu + ((u >> 16) & 1u)) >> 16);  // RNE
}
__device__ __forceinline__ float bf2f(unsigned short s) {
  union { uint32_t u; float f; } x; x.u = ((uint32_t)s) << 16; return x.f;
}

// ---------------- fp32 -> bf16 cast, 8 elems/thread ----------------
__global__ __launch_bounds__(256) void cvt_kernel(const float* __restrict__ in,
                                                  unsigned short* __restrict__ out, int n8) {
  int i = blockIdx.x * 256 + threadIdx.x;
  if (i >= n8) return;
  long base = (long)i * 8;
  const float4* p = (const float4*)(in + base);
  float4 a = p[0], b = p[1];
  ushort8 r;
  r[0] = f2bf(a.x); r[1] = f2bf(a.y); r[2] = f2bf(a.z); r[3] = f2bf(a.w);
  r[4] = f2bf(b.x); r[5] = f2bf(b.y); r[6] = f2bf(b.z); r[7] = f2bf(b.w);
  *(ushort8*)(out + base) = r;
}

// ---------------- async global->LDS, 16B per lane ----------------
__device__ __forceinline__ void gl2lds16(const void* g, void* l) {
  __builtin_amdgcn_global_load_lds(
      (const uint32_t __attribute__((address_space(1)))*)g,
      (uint32_t __attribute__((address_space(3)))*)(uint32_t)(uintptr_t)l,
      16, 0, 0);
}

// ---------------- bf16 GEMM v2: C[M,N] = A[M,K]*B[N,K]^T + bias[N] ----------------
// 128x128 tile, BK=64, 4 waves of 64x64 = 2x2 mfma_f32_32x32x16_bf16 sub-tiles.
// LDS layout: 16B chunks at L = r*8 + (c ^ (r&7)), c = k-chunk (8 bf16), r = row.
// -> global staging stays coalesced (permutation within 128B row segments),
//    fragment ds_read_b128 is uniformly bank-distributed.
template <bool OUT_BF16>
__device__ __forceinline__ void gemm_core(const unsigned short* __restrict__ A,
                                          const unsigned short* __restrict__ Bm,
                                          const float* __restrict__ bias,
                                          void* __restrict__ Cout, int N, int K) {
  __shared__ __align__(16) unsigned short lA[128 * 64];
  __shared__ __align__(16) unsigned short lB[128 * 64];
  const int tid = threadIdx.x;
  const int lane = tid & 63;
  const int wave = tid >> 6;
  const long row0 = (long)blockIdx.y * 128;
  const long col0 = (long)blockIdx.x * 128;
  const int wr = (wave & 1) * 64;
  const int wc = (wave >> 1) * 64;
  const int l32 = lane & 31;
  const int lhi = lane >> 5;
  const int l7 = lane & 7;

  floatx16 acc[2][2] = {};

  // ---- staging addresses ----
  // thread covers chunks L = p*256 + tid, p=0..3, per matrix.
  // r = p*32 + (tid>>3)   (row), swz = tid&7, global c = swz ^ (r&7) = (tid&7)^((tid>>3)&7)
  const int rstage = tid >> 3;
  const int cstage = (tid & 7) ^ (rstage & 7);
  const unsigned short* gA0 = A + (row0 + rstage) * (long)K + cstage * 8;
  const unsigned short* gB0 = Bm + (col0 + rstage) * (long)K + cstage * 8;
  char* ldsA0 = (char*)lA + tid * 16;
  char* ldsB0 = (char*)lB + tid * 16;
  const long rowstep = (long)32 * K;  // p advances row by 32

  // ---- fragment read offsets (bytes) ----
  // A: row r = wr + i*32 + l32, chunk c = 2s + lhi, stored at byte r*128 + ((c^l7))*16
  int aRow[2], bRow[2], sOff[4];
#pragma unroll
  for (int i = 0; i < 2; i++) aRow[i] = (wr + i * 32 + l32) * 128;
#pragma unroll
  for (int j = 0; j < 2; j++) bRow[j] = (wc + j * 32 + l32) * 128;
#pragma unroll
  for (int s = 0; s < 4; s++) sOff[s] = ((2 * s + lhi) ^ l7) * 16;

  for (int k0 = 0; k0 < K; k0 += 64) {
    __syncthreads();
#pragma unroll
    for (int p = 0; p < 4; p++) {
      gl2lds16(gA0 + p * rowstep + k0, ldsA0 + p * 4096);
      gl2lds16(gB0 + p * rowstep + k0, ldsB0 + p * 4096);
    }
    __syncthreads();

#pragma unroll
    for (int s = 0; s < 4; s++) {
      short8 a0 = *(const short8*)((char*)lA + aRow[0] + sOff[s]);
      short8 a1 = *(const short8*)((char*)lA + aRow[1] + sOff[s]);
      short8 b0 = *(const short8*)((char*)lB + bRow[0] + sOff[s]);
      short8 b1 = *(const short8*)((char*)lB + bRow[1] + sOff[s]);
      acc[0][0] = __builtin_amdgcn_mfma_f32_32x32x16_bf16(a0, b0, acc[0][0], 0, 0, 0);
      acc[0][1] = __builtin_amdgcn_mfma_f32_32x32x16_bf16(a0, b1, acc[0][1], 0, 0, 0);
      acc[1][0] = __builtin_amdgcn_mfma_f32_32x32x16_bf16(a1, b0, acc[1][0], 0, 0, 0);
      acc[1][1] = __builtin_amdgcn_mfma_f32_32x32x16_bf16(a1, b1, acc[1][1], 0, 0, 0);
    }
  }

  // ---- epilogue: C/D layout col = lane&31, row = (reg&3) + 8*(reg>>2) + 4*(lane>>5) ----
  float bv[2];
#pragma unroll
  for (int j = 0; j < 2; j++) bv[j] = bias[col0 + wc + j * 32 + l32];

#pragma unroll
  for (int i = 0; i < 2; i++) {
#pragma unroll
    for (int j = 0; j < 2; j++) {
      const long col = col0 + wc + j * 32 + l32;
      const long rbase = row0 + wr + i * 32 + 4 * lhi;
#pragma unroll
      for (int reg = 0; reg < 16; reg++) {
        const long row = rbase + (reg & 3) + 8 * (reg >> 2);
        float v = acc[i][j][reg] + bv[j];
        if (OUT_BF16)
          ((unsigned short*)Cout)[row * N + col] = f2bf(v);
        else
          ((float*)Cout)[row * N + col] = v;
      }
    }
  }
}

__global__ __launch_bounds__(256) void gemm_qkv(const unsigned short* __restrict__ A,
                                                const unsigned short* __restrict__ Bm,
                                                const float* __restrict__ bias,
                                                unsigned short* __restrict__ Cout,
                                                int N, int K) {
  gemm_core<true>(A, Bm, bias, Cout, N, K);
}

__global__ __launch_bounds__(256) void gemm_out(const unsigned short* __restrict__ A,
                                                const unsigned short* __restrict__ Bm,
                                                const float* __restrict__ bias,
                                                float* __restrict__ Cout,
                                                int N, int K) {
  gemm_core<false>(A, Bm, bias, Cout, N, K);
}

// ---------------- per-token cross-head attention ----------------
// energy[b,s,i,j] = sum_d Q[b,s,i,d]*K[b,s,j,d] / 32; softmax over j; out = A*V,
// written with raw-reshape scramble: row = b*2048 + i*128 + s/16, col = (s%16)*64 + d.
__global__ __launch_bounds__(256) void attn_kernel(const unsigned short* __restrict__ qkv,
                                                   unsigned short* __restrict__ out2) {
  const int t = blockIdx.x * 256 + threadIdx.x;  // (token, head)
  const int head = t & 15;
  const int token = t >> 4;
  const int b = token >> 11;
  const int s = token & 2047;
  const unsigned short* base = qkv + (long)token * 3072;

  float qf[64];
  {
    const uint4* qp = (const uint4*)(base + head * 64);
#pragma unroll
    for (int w = 0; w < 8; w++) {
      uint4 u = qp[w];
      uint32_t arr[4] = {u.x, u.y, u.z, u.w};
#pragma unroll
      for (int c = 0; c < 4; c++) {
        qf[w * 8 + c * 2 + 0] = bf2f((unsigned short)(arr[c] & 0xffffu));
        qf[w * 8 + c * 2 + 1] = bf2f((unsigned short)(arr[c] >> 16));
      }
    }
  }

  float e[16];
  const unsigned short* kbase = base + 1024;
  for (int j = 0; j < 16; j++) {
    const uint4* kp = (const uint4*)(kbase + j * 64);
    float acc = 0.f;
#pragma unroll
    for (int w = 0; w < 8; w++) {
      uint4 u = kp[w];
      uint32_t arr[4] = {u.x, u.y, u.z, u.w};
#pragma unroll
      for (int c = 0; c < 4; c++) {
        acc += qf[w * 8 + c * 2 + 0] * bf2f((unsigned short)(arr[c] & 0xffffu));
        acc += qf[w * 8 + c * 2 + 1] * bf2f((unsigned short)(arr[c] >> 16));
      }
    }
    e[j] = acc * 0.03125f;  // / sqrt(1024)
  }

  float mx = e[0];
#pragma unroll
  for (int j = 1; j < 16; j++) mx = fmaxf(mx, e[j]);
  float p[16];
  float sum = 0.f;
#pragma unroll
  for (int j = 0; j < 16; j++) { p[j] = __expf(e[j] - mx); sum += p[j]; }
  const float inv = 1.f / sum;

  float o[64];
#pragma unroll
  for (int d = 0; d < 64; d++) o[d] = 0.f;
  const unsigned short* vbase = base + 2048;
  for (int j = 0; j < 16; j++) {
    const float wgt = p[j] * inv;
    const uint4* vp = (const uint4*)(vbase + j * 64);
#pragma unroll
    for (int w = 0; w < 8; w++) {
      uint4 u = vp[w];
      uint32_t arr[4] = {u.x, u.y, u.z, u.w};
#pragma unroll
      for (int c = 0; c < 4; c++) {
        o[w * 8 + c * 2 + 0] += wgt * bf2f((unsigned short)(arr[c] & 0xffffu));
        o[w * 8 + c * 2 + 1] += wgt * bf2f((unsigned short)(arr[c] >> 16));
      }
    }
  }

  const long row = (long)b * 2048 + head * 128 + (s >> 4);
  unsigned short* op = out2 + row * 1024 + (long)(s & 15) * 64;
#pragma unroll
  for (int w = 0; w < 8; w++) {
    ushort8 r;
#pragma unroll
    for (int c = 0; c < 8; c++) r[c] = f2bf(o[w * 8 + c]);
    *(ushort8*)(op + w * 8) = r;
  }
}

extern "C" void kernel_launch(void* const* d_in, const int* in_sizes, int n_in,
                              void* d_out, int out_size, void* d_ws, size_t ws_size,
                              hipStream_t stream) {
  const float* x    = (const float*)d_in[0];  // [8,2048,1024]
  const float* Wqkv = (const float*)d_in[1];  // [3072,1024]
  const float* bqkv = (const float*)d_in[2];  // [3072]
  const float* Wo   = (const float*)d_in[3];  // [1024,1024]
  const float* bo   = (const float*)d_in[4];  // [1024]
  float* out = (float*)d_out;                 // [8,2048,1024] fp32

  char* ws = (char*)d_ws;
  unsigned short* x_bf    = (unsigned short*)(ws);              // 32 MB
  unsigned short* wqkv_bf = (unsigned short*)(ws + 33554432);   // 6 MB
  unsigned short* wo_bf   = (unsigned short*)(ws + 39845888);   // 2 MB
  unsigned short* qkv_bf  = (unsigned short*)(ws + 41943040);   // 96 MB
  unsigned short* out2_bf = (unsigned short*)(ws + 142606336);  // 32 MB

  cvt_kernel<<<8192, 256, 0, stream>>>(x, x_bf, 16777216 / 8);
  cvt_kernel<<<1536, 256, 0, stream>>>(Wqkv, wqkv_bf, 3145728 / 8);
  cvt_kernel<<<512, 256, 0, stream>>>(Wo, wo_bf, 1048576 / 8);

  dim3 g1(3072 / 128, 16384 / 128);
  gemm_qkv<<<g1, 256, 0, stream>>>(x_bf, wqkv_bf, bqkv, qkv_bf, 3072, 1024);

  attn_kernel<<<1024, 256, 0, stream>>>(qkv_bf, out2_bf);

  dim3 g2(1024 / 128, 16384 / 128);
  gemm_out<<<g2, 256, 0, stream>>>(out2_bf, wo_bf, bo, out, 1024, 1024);
}